// Round 8
// baseline (12237.043 us; speedup 1.0000x reference)
//
#include <hip/hip_runtime.h>

typedef unsigned short u16;
typedef float f32x4 __attribute__((ext_vector_type(4)));
typedef short s16x8 __attribute__((ext_vector_type(8)));

#define T_TOK   16448L   // 257*64
#define D_DIM   768L
#define H_DIM   3072L
#define E_NUM   8L
#define M_PAD   16640L   // 65*256 ; halves: A=8192 rows (32 tiles), B=8448 rows (33 tiles)

// ---------- helpers ----------
__device__ __forceinline__ u16 f2bf(float f){
  unsigned u = __float_as_uint(f);
  u = u + 0x7FFFu + ((u >> 16) & 1u);          // RNE
  return (u16)(u >> 16);
}
__device__ __forceinline__ unsigned f2bf2(float a, float b){
  return (unsigned)f2bf(a) | ((unsigned)f2bf(b) << 16);
}

__device__ __forceinline__ void gload_lds16(const u16* g, u16* s){
  __builtin_amdgcn_global_load_lds((const __attribute__((address_space(1))) void*)g,
                                   (__attribute__((address_space(3))) void*)s,
                                   16, 0, 0);
}

// bijective XCD chunking (m204)
__device__ __forceinline__ int xcd_chunk(int idx, int n){
  const int q = n >> 3, r = n & 7, x = idx & 7;
  return (x < r ? x*(q+1) : r*(q+1) + (x-r)*q) + (idx >> 3);
}

// ---------- fp32 -> bf16 (zero-padded tail) ----------
__global__ void k_conv(const float* __restrict__ in, u16* __restrict__ outp,
                       long nValid, long nTotal){
  long i = (long)blockIdx.x * blockDim.x + threadIdx.x;
  long stride = (long)gridDim.x * blockDim.x;
  long n8 = nTotal >> 3;
  for (long v = i; v < n8; v += stride){
    long base = v << 3;
    uint4 o;
    if (base < nValid){
      const float4 f0 = *(const float4*)(in + base);
      const float4 f1 = *(const float4*)(in + base + 4);
      o.x = f2bf2(f0.x, f0.y); o.y = f2bf2(f0.z, f0.w);
      o.z = f2bf2(f1.x, f1.y); o.w = f2bf2(f1.z, f1.w);
    } else {
      o.x = 0u; o.y = 0u; o.z = 0u; o.w = 0u;
    }
    *(uint4*)(outp + base) = o;
  }
}

// ---------- router: logits + softmax (fp32, one wave per token) ----------
__global__ void k_router(const float* __restrict__ x, const float* __restrict__ Wr,
                         const float* __restrict__ br, float* __restrict__ probs){
  int w = (int)((blockIdx.x * (long)blockDim.x + threadIdx.x) >> 6);
  int lane = threadIdx.x & 63;
  if (w >= (int)T_TOK) return;
  const float* xr = x + (long)w * D_DIM;
  float l[8];
#pragma unroll
  for (int e = 0; e < 8; ++e) l[e] = 0.f;
#pragma unroll
  for (int c = 0; c < 3; ++c){
    const float4 xv = *(const float4*)(xr + c*256 + lane*4);
#pragma unroll
    for (int e = 0; e < 8; ++e){
      const float4 wv = *(const float4*)(Wr + (long)e*D_DIM + c*256 + lane*4);
      l[e] += xv.x*wv.x + xv.y*wv.y + xv.z*wv.z + xv.w*wv.w;
    }
  }
#pragma unroll
  for (int e = 0; e < 8; ++e){
#pragma unroll
    for (int off = 32; off > 0; off >>= 1) l[e] += __shfl_xor(l[e], off);
    l[e] += br[e];
  }
  float m = l[0];
#pragma unroll
  for (int e = 1; e < 8; ++e) m = fmaxf(m, l[e]);
  float s = 0.f;
#pragma unroll
  for (int e = 0; e < 8; ++e){ l[e] = __expf(l[e] - m); s += l[e]; }
  float inv = 1.f / s;
  if (lane == 0){
    float4 p0 = { l[0]*inv, l[1]*inv, l[2]*inv, l[3]*inv };
    float4 p1 = { l[4]*inv, l[5]*inv, l[6]*inv, l[7]*inv };
    *(float4*)(probs + (long)w*8)     = p0;
    *(float4*)(probs + (long)w*8 + 4) = p1;
  }
}

#define FENCE()  __builtin_amdgcn_sched_barrier(0)
#define BAR()    do{ FENCE(); __builtin_amdgcn_s_barrier(); FENCE(); }while(0)

// ---------- 256x256 GEMM, BK=32, 2-deep double buffer (64 KiB -> 2 blocks/CU) ----------
// LDS: 2 buffers x (A 256x32 | B 256x32) bf16 = 2 x 32 KB.
// Rows are 32 elems (64 B), 4 16B-slots; LDS[r][s] holds source chunk s ^ (r&3)
// (pre-swizzled source, lane-linear dest; readers apply the same involution).
__device__ __forceinline__ void gemm256_k32(const u16* __restrict__ Ag, long lda,
                                            const u16* __restrict__ Bg, long ldb,
                                            int NT, u16* lds, int tid,
                                            f32x4 (&acc)[8][4]){
  const int l  = tid & 63, w = tid >> 6;
  const int wr = w >> 2,  wc = w & 3;
  const int g4 = l >> 4,  ln = l & 15;

  // staging: per-thread loop-invariant sources/dests (2 A-gloads + 2 B-gloads/tile)
  const int rw16 = l >> 2;                        // row within 16-row group
  const int scol = ((l & 3) ^ (rw16 & 3)) << 3;   // swizzled source chunk (elems)
  const u16* gA0 = Ag + (long)(      w*16 + rw16) * lda + scol;
  const u16* gA1 = Ag + (long)(128 + w*16 + rw16) * lda + scol;
  const u16* gB0 = Bg + (long)(      w*16 + rw16) * ldb + scol;
  const u16* gB1 = Bg + (long)(128 + w*16 + rw16) * ldb + scol;
  u16* dA0 = lds +        w*512;                  // + buf*16384
  u16* dA1 = lds + 4096 + w*512;
  u16* dB0 = lds + 8192 +        w*512;
  u16* dB1 = lds + 8192 + 4096 + w*512;

  // ds_read element offsets (loop-invariant); r&3 == ln&3 since rbase % 16 == 0
  const int sw = (g4 ^ (ln & 3)) << 3;
  int offA[8], offB[4];
#pragma unroll
  for (int mi = 0; mi < 8; ++mi) offA[mi] = (wr*128 + mi*16 + ln)*32 + sw;
#pragma unroll
  for (int ni = 0; ni < 4; ++ni) offB[ni] = 8192 + (wc*64 + ni*16 + ln)*32 + sw;

  // prologue: stage tiles 0,1 into bufs 0,1; wait tile 0 (tile 1 in flight)
#pragma unroll
  for (int t = 0; t < 2; ++t){
    const long ko = (long)t * 32;
    const int  bo = t * 16384;
    gload_lds16(gA0 + ko, dA0 + bo);
    gload_lds16(gA1 + ko, dA1 + bo);
    gload_lds16(gB0 + ko, dB0 + bo);
    gload_lds16(gB1 + ko, dB1 + bo);
  }
  FENCE();
  asm volatile("s_waitcnt vmcnt(4)" ::: "memory");
  BAR();

  for (int kt = 0; kt < NT; ++kt){
    const u16* base = lds + (kt & 1) * 16384;
    s16x8 a[8], b[4];
#pragma unroll
    for (int ni = 0; ni < 4; ++ni) b[ni] = *(const s16x8*)(base + offB[ni]);
#pragma unroll
    for (int mi = 0; mi < 8; ++mi) a[mi] = *(const s16x8*)(base + offA[mi]);
#pragma unroll
    for (int mi = 0; mi < 8; ++mi)
#pragma unroll
      for (int ni = 0; ni < 4; ++ni)
        acc[mi][ni] = __builtin_amdgcn_mfma_f32_16x16x32_bf16(a[mi], b[ni], acc[mi][ni], 0, 0, 0);

    if (kt + 1 < NT){
      BAR();                                   // all waves consumed buf[kt&1]
      if (kt + 2 < NT){                        // stage tile kt+2 into retired buf
        const long ko = (long)(kt + 2) * 32;
        const int  bo = (kt & 1) * 16384;
        gload_lds16(gA0 + ko, dA0 + bo);
        gload_lds16(gA1 + ko, dA1 + bo);
        gload_lds16(gB0 + ko, dB0 + bo);
        gload_lds16(gB1 + ko, dB1 + bo);
        FENCE();
        asm volatile("s_waitcnt vmcnt(4)" ::: "memory");  // kt+1 landed; kt+2 in flight
      } else {
        FENCE();
        asm volatile("s_waitcnt vmcnt(0)" ::: "memory");  // tail: drain
      }
      BAR();                                   // tile kt+1 visible to all waves
    }
  }
}

// ---------- paired dispatch: gemm2(e2, one token-half) + gemm1(e1, other half) ----------
__global__ __launch_bounds__(512, 4) void k_pair(const u16* __restrict__ xb,
                                                 const u16* __restrict__ w1b,
                                                 const float* __restrict__ b1,
                                                 const u16* __restrict__ w2b,
                                                 const float* __restrict__ b2,
                                                 const float* __restrict__ probs,
                                                 float* __restrict__ out,
                                                 const u16* __restrict__ hbR,
                                                 u16* __restrict__ hbW,
                                                 int e2, int t02,
                                                 int e1, int t01, int mt1, int n2){
  __shared__ alignas(16) u16 lds[32768];   // 64 KiB: 2 bufs x (A 8192 | B 8192 elems)
  const int tid = threadIdx.x;
  const int l  = tid & 63, w = tid >> 6;
  const int wr = w >> 2,  wc = w & 3;
  const int g4 = l >> 4,  ln = l & 15;
  const int bx = (int)blockIdx.x;
  f32x4 acc[8][4] = {};

  if (bx < n2){
    // ---- gemm2: XCD-chunked, y-fastest (3 N-tiles share the A-panel) ----
    const int wg = xcd_chunk(bx, n2);
    const int tx = wg / 3, ty = wg % 3;
    const int m0 = tx << 8, n0 = ty << 8;
    gemm256_k32(hbR + (long)m0 * H_DIM, H_DIM,
                w2b + ((long)e2 * D_DIM + n0) * H_DIM, H_DIM,
                96, lds, tid, acc);
    float bias[4];
#pragma unroll
    for (int ni = 0; ni < 4; ++ni) bias[ni] = b2[(long)e2*D_DIM + n0 + wc*64 + ni*16 + ln];
#pragma unroll
    for (int mi = 0; mi < 8; ++mi){
#pragma unroll
      for (int j = 0; j < 4; ++j){
        const int gt = t02 + m0 + wr*128 + mi*16 + g4*4 + j;
        if (gt < (int)T_TOK){
          const float p = probs[(long)gt*8 + e2];
          float* dst = out + (long)gt * D_DIM + n0 + wc*64;
#pragma unroll
          for (int ni = 0; ni < 4; ++ni){
            const float v = p * (acc[mi][ni][j] + bias[ni]);
            if (e2 == 0) dst[ni*16 + ln] = v;
            else         dst[ni*16 + ln] += v;
          }
        }
      }
    }
  } else {
    // ---- gemm1: XCD-chunked, x-fastest (B-panel reused along chunk) ----
    const int n1 = (int)gridDim.x - n2;
    const int wg = xcd_chunk(bx - n2, n1);
    const int tx = wg % mt1, ty = wg / mt1;
    const int m0 = tx << 8, n0 = ty << 8;
    gemm256_k32(xb + (long)(t01 + m0) * D_DIM, D_DIM,
                w1b + ((long)e1 * H_DIM + n0) * D_DIM, D_DIM,
                24, lds, tid, acc);
    float bias[4];
#pragma unroll
    for (int ni = 0; ni < 4; ++ni) bias[ni] = b1[(long)e1*H_DIM + n0 + wc*64 + ni*16 + ln];
#pragma unroll
    for (int mi = 0; mi < 8; ++mi){
#pragma unroll
      for (int j = 0; j < 4; ++j){
        const int r = m0 + wr*128 + mi*16 + g4*4 + j;     // half-local row
        u16* dst = hbW + (long)r * H_DIM + n0 + wc*64;
#pragma unroll
        for (int ni = 0; ni < 4; ++ni){
          const float v  = acc[mi][ni][j] + bias[ni];
          const float gl = v / (1.0f + __expf(-1.702f * v));  // quick_gelu
          dst[ni*16 + ln] = f2bf(gl);
        }
      }
    }
  }
}

// ---------- host ----------
extern "C" void kernel_launch(void* const* d_in, const int* in_sizes, int n_in,
                              void* d_out, int out_size, void* d_ws, size_t ws_size,
                              hipStream_t stream){
  const float* x  = (const float*)d_in[0];
  const float* W1 = (const float*)d_in[1];
  const float* b1 = (const float*)d_in[2];
  const float* W2 = (const float*)d_in[3];
  const float* b2 = (const float*)d_in[4];
  const float* Wr = (const float*)d_in[5];
  const float* br = (const float*)d_in[6];
  float* out = (float*)d_out;

  char* ws = (char*)d_ws;
  size_t off = 0;
  auto carve = [&](size_t bytes)->void*{
    void* p = ws + off; off += (bytes + 255) & ~(size_t)255; return p;
  };
  u16*   xb    = (u16*)  carve((size_t)M_PAD * D_DIM * 2);
  u16*   w1b   = (u16*)  carve((size_t)E_NUM * H_DIM * D_DIM * 2);
  u16*   w2b   = (u16*)  carve((size_t)E_NUM * D_DIM * H_DIM * 2);
  float* probs = (float*)carve((size_t)T_TOK * E_NUM * 4);
  u16*   hbA   = (u16*)  carve((size_t)8192 * H_DIM * 2);   // tokens [0, 8192)
  u16*   hbB   = (u16*)  carve((size_t)8448 * H_DIM * 2);   // tokens [8192, 16640)

  // conversions + router
  k_conv<<<dim3(2048), dim3(256), 0, stream>>>(x,  xb,  T_TOK*D_DIM, M_PAD*D_DIM);
  k_conv<<<dim3(2048), dim3(256), 0, stream>>>(W1, w1b, E_NUM*H_DIM*D_DIM, E_NUM*H_DIM*D_DIM);
  k_conv<<<dim3(2048), dim3(256), 0, stream>>>(W2, w2b, E_NUM*D_DIM*H_DIM, E_NUM*D_DIM*H_DIM);
  k_router<<<dim3(4112), dim3(256), 0, stream>>>(x, Wr, br, probs);

  const int MTA = 32, MTB = 33;      // 256-row tile counts per token-half
  const int T0A = 0,  T0B = 8192;

  auto pair = [&](int e2, const u16* hbR, int t02, int mt2,
                  int e1, u16* hbW, int t01, int mt1){
    const int n2 = mt2 * 3, n1 = mt1 * 12;
    k_pair<<<dim3((unsigned)(n2 + n1)), dim3(512), 0, stream>>>(
        xb, w1b, b1, w2b, b2, probs, out, hbR, hbW,
        e2, t02, e1, t01, mt1, n2);
  };

  // ping-pong: D0: g1(0,A); D(2e+1): g2(e,A)+g1(e,B); D(2e+2): g2(e,B)+g1(e+1,A); D16: g2(7,B)
  pair(0, nullptr, 0, 0, 0, hbA, T0A, MTA);
  for (int e = 0; e < 8; ++e){
    pair(e, hbA, T0A, MTA, e, hbB, T0B, MTB);
    if (e < 7) pair(e, hbB, T0B, MTB, e + 1, hbA, T0A, MTA);
  }
  pair(7, hbB, T0B, MTB, 0, nullptr, 0, 0);
}

// Round 9
// 2003.134 us; speedup vs baseline: 6.1089x; 6.1089x over previous
//
#include <hip/hip_runtime.h>

typedef unsigned short u16;
typedef float f32x4 __attribute__((ext_vector_type(4)));
typedef short s16x8 __attribute__((ext_vector_type(8)));

#define T_TOK   16448L   // 257*64
#define D_DIM   768L
#define H_DIM   3072L
#define E_NUM   8L
#define M_PAD   16640L   // 65*256 ; halves: A=8192 rows (32 tiles), B=8448 rows (33 tiles)

// ---------- helpers ----------
__device__ __forceinline__ u16 f2bf(float f){
  unsigned u = __float_as_uint(f);
  u = u + 0x7FFFu + ((u >> 16) & 1u);          // RNE
  return (u16)(u >> 16);
}
__device__ __forceinline__ unsigned f2bf2(float a, float b){
  return (unsigned)f2bf(a) | ((unsigned)f2bf(b) << 16);
}

__device__ __forceinline__ void gload_lds16(const u16* g, u16* s){
  __builtin_amdgcn_global_load_lds((const __attribute__((address_space(1))) void*)g,
                                   (__attribute__((address_space(3))) void*)s,
                                   16, 0, 0);
}

// bijective XCD chunking (m204)
__device__ __forceinline__ int xcd_chunk(int idx, int n){
  const int q = n >> 3, r = n & 7, x = idx & 7;
  return (x < r ? x*(q+1) : r*(q+1) + (x-r)*q) + (idx >> 3);
}

// ---------- fp32 -> bf16 (zero-padded tail) ----------
__global__ void k_conv(const float* __restrict__ in, u16* __restrict__ outp,
                       long nValid, long nTotal){
  long i = (long)blockIdx.x * blockDim.x + threadIdx.x;
  long stride = (long)gridDim.x * blockDim.x;
  long n8 = nTotal >> 3;
  for (long v = i; v < n8; v += stride){
    long base = v << 3;
    uint4 o;
    if (base < nValid){
      const float4 f0 = *(const float4*)(in + base);
      const float4 f1 = *(const float4*)(in + base + 4);
      o.x = f2bf2(f0.x, f0.y); o.y = f2bf2(f0.z, f0.w);
      o.z = f2bf2(f1.x, f1.y); o.w = f2bf2(f1.z, f1.w);
    } else {
      o.x = 0u; o.y = 0u; o.z = 0u; o.w = 0u;
    }
    *(uint4*)(outp + base) = o;
  }
}

// ---------- router: logits + softmax (fp32, one wave per token) ----------
__global__ void k_router(const float* __restrict__ x, const float* __restrict__ Wr,
                         const float* __restrict__ br, float* __restrict__ probs){
  int w = (int)((blockIdx.x * (long)blockDim.x + threadIdx.x) >> 6);
  int lane = threadIdx.x & 63;
  if (w >= (int)T_TOK) return;
  const float* xr = x + (long)w * D_DIM;
  float l[8];
#pragma unroll
  for (int e = 0; e < 8; ++e) l[e] = 0.f;
#pragma unroll
  for (int c = 0; c < 3; ++c){
    const float4 xv = *(const float4*)(xr + c*256 + lane*4);
#pragma unroll
    for (int e = 0; e < 8; ++e){
      const float4 wv = *(const float4*)(Wr + (long)e*D_DIM + c*256 + lane*4);
      l[e] += xv.x*wv.x + xv.y*wv.y + xv.z*wv.z + xv.w*wv.w;
    }
  }
#pragma unroll
  for (int e = 0; e < 8; ++e){
#pragma unroll
    for (int off = 32; off > 0; off >>= 1) l[e] += __shfl_xor(l[e], off);
    l[e] += br[e];
  }
  float m = l[0];
#pragma unroll
  for (int e = 1; e < 8; ++e) m = fmaxf(m, l[e]);
  float s = 0.f;
#pragma unroll
  for (int e = 0; e < 8; ++e){ l[e] = __expf(l[e] - m); s += l[e]; }
  float inv = 1.f / s;
  if (lane == 0){
    float4 p0 = { l[0]*inv, l[1]*inv, l[2]*inv, l[3]*inv };
    float4 p1 = { l[4]*inv, l[5]*inv, l[6]*inv, l[7]*inv };
    *(float4*)(probs + (long)w*8)     = p0;
    *(float4*)(probs + (long)w*8 + 4) = p1;
  }
}

#define FENCE()  __builtin_amdgcn_sched_barrier(0)
#define BAR()    do{ FENCE(); __builtin_amdgcn_s_barrier(); FENCE(); }while(0)
#define LGK0()   do{ asm volatile("s_waitcnt lgkmcnt(0)" ::: "memory"); FENCE(); }while(0)

// read one 16-row MFMA fragment: rows rbase..rbase+15, logical k-chunk c (0..7)
__device__ __forceinline__ s16x8 ld_frag(const u16* S, int rbase, int c, int ln){
  const int r = rbase + ln;
  return *(const s16x8*)(S + (r << 6) + ((c ^ (r & 7)) << 3));
}

// ---------- 256x256 GEMM, BK=64, m201-style 4-phase fine interleave ----------
// LDS: 2 bufs x (A 256x64 | B 256x64) bf16 = 2 x 64 KB. Rows 64 elems, chunk
// swizzle s ^ (r&7) on source + read (proven conflict-free, r6).
// Per phase: {ds_read subtile ; 2 global_load_lds ; BAR ; lgkmcnt0 ; 16 MFMA
// (setprio-wrapped) ; BAR}. Quarter-retirement staging map:
//   A rows 0-63,128-191 + all B retire after ph1 ; A rows 64-127,192-255 after ph3.
//   ph0: A(t+1) r1, B(t+1) r2 -> other buf   ph1: A(t+1) r3, B(t+1) r3 -> other
//   ph2: A(t+2) r0, B(t+2) r0 -> cur buf     ph3: A(t+2) r2, B(t+2) r1 -> cur
// Boundary: vmcnt(4) (t+2's 4 loads stay in flight), 0 only in tail.
__device__ __forceinline__ void gemm256(const u16* __restrict__ Ag, long lda,
                                        const u16* __restrict__ Bg, long ldb,
                                        int NT, u16* lds, int tid,
                                        f32x4 (&acc)[8][4]){
  const int l  = tid & 63, w = tid >> 6;
  const int wr = w >> 2,  wc = w & 3;
  const int g4 = l >> 4,  ln = l & 15;

  // per-thread staging bases (2 loads/phase; round rnd = 64-row quarter)
  const int rw = l >> 3;
  const int c8 = (l & 7) ^ rw;
  const u16* gA = Ag + (long)(w*8 + rw) * lda + c8*8;
  const u16* gB = Bg + (long)(w*8 + rw) * ldb + c8*8;
  u16* s0 = lds + w*512;
#define SA(par,T,rnd) gload_lds16(gA + (long)(T)*64 + (long)(rnd)*64*lda, s0 + (par)*32768 + (rnd)*4096)
#define SB(par,T,rnd) gload_lds16(gB + (long)(T)*64 + (long)(rnd)*64*ldb, s0 + (par)*32768 + 16384 + (rnd)*4096)

  // prologue: t0 full (8 loads), t1 early-half (4) -> wait t0 (t1's 4 in flight)
#pragma unroll
  for (int i = 0; i < 4; ++i) SA(0,0,i);
#pragma unroll
  for (int i = 0; i < 4; ++i) SB(0,0,i);
  SA(1,1,0); SB(1,1,0); SA(1,1,2); SB(1,1,1);
  FENCE();
  asm volatile("s_waitcnt vmcnt(4)" ::: "memory");
  BAR();

  for (int kt = 0; kt < NT; ++kt){
    const int par = kt & 1, oth = par ^ 1;
    const u16* As = lds + par * 32768;
    const u16* Bs = As + 16384;
    const bool st1 = (kt + 1 < NT), st2 = (kt + 2 < NT);
    s16x8 aL[4], aH[4], b0[4], b1[4];

    // ---- ph0: B kh0 + A-low kh0 ; MFMA acc[0-3] x b0 ----
#pragma unroll
    for (int ni = 0; ni < 4; ++ni) b0[ni] = ld_frag(Bs, wc*64 + ni*16, g4, ln);
#pragma unroll
    for (int mi = 0; mi < 4; ++mi) aL[mi] = ld_frag(As, wr*128 + mi*16, g4, ln);
    if (st1){ SA(oth, kt+1, 1); SB(oth, kt+1, 2); }
    BAR(); LGK0();
    __builtin_amdgcn_s_setprio(1);
#pragma unroll
    for (int mi = 0; mi < 4; ++mi)
#pragma unroll
      for (int ni = 0; ni < 4; ++ni)
        acc[mi][ni] = __builtin_amdgcn_mfma_f32_16x16x32_bf16(aL[mi], b0[ni], acc[mi][ni], 0, 0, 0);
    __builtin_amdgcn_s_setprio(0);
    BAR();

    // ---- ph1: B kh1 + A-low kh1 ; MFMA acc[0-3] x b1 ----
#pragma unroll
    for (int ni = 0; ni < 4; ++ni) b1[ni] = ld_frag(Bs, wc*64 + ni*16, 4 + g4, ln);
#pragma unroll
    for (int mi = 0; mi < 4; ++mi) aL[mi] = ld_frag(As, wr*128 + mi*16, 4 + g4, ln);
    if (st1){ SA(oth, kt+1, 3); SB(oth, kt+1, 3); }
    BAR(); LGK0();
    __builtin_amdgcn_s_setprio(1);
#pragma unroll
    for (int mi = 0; mi < 4; ++mi)
#pragma unroll
      for (int ni = 0; ni < 4; ++ni)
        acc[mi][ni] = __builtin_amdgcn_mfma_f32_16x16x32_bf16(aL[mi], b1[ni], acc[mi][ni], 0, 0, 0);
    __builtin_amdgcn_s_setprio(0);
    BAR();
    // A rows 0-63/128-191 + all B of cur buf now retired

    // ---- ph2: A-high kh0 ; MFMA acc[4-7] x b0 (b0 register-carried) ----
#pragma unroll
    for (int mi = 0; mi < 4; ++mi) aH[mi] = ld_frag(As, wr*128 + 64 + mi*16, g4, ln);
    if (st2){ SA(par, kt+2, 0); SB(par, kt+2, 0); }
    BAR(); LGK0();
    __builtin_amdgcn_s_setprio(1);
#pragma unroll
    for (int mi = 0; mi < 4; ++mi)
#pragma unroll
      for (int ni = 0; ni < 4; ++ni)
        acc[mi+4][ni] = __builtin_amdgcn_mfma_f32_16x16x32_bf16(aH[mi], b0[ni], acc[mi+4][ni], 0, 0, 0);
    __builtin_amdgcn_s_setprio(0);
    BAR();

    // ---- ph3: A-high kh1 ; MFMA acc[4-7] x b1 ; boundary ----
#pragma unroll
    for (int mi = 0; mi < 4; ++mi) aH[mi] = ld_frag(As, wr*128 + 64 + mi*16, 4 + g4, ln);
    if (st2){ SA(par, kt+2, 2); SB(par, kt+2, 1); }
    BAR(); LGK0();
    __builtin_amdgcn_s_setprio(1);
#pragma unroll
    for (int mi = 0; mi < 4; ++mi)
#pragma unroll
      for (int ni = 0; ni < 4; ++ni)
        acc[mi+4][ni] = __builtin_amdgcn_mfma_f32_16x16x32_bf16(aH[mi], b1[ni], acc[mi+4][ni], 0, 0, 0);
    __builtin_amdgcn_s_setprio(0);

    if (st1){
      FENCE();
      if (st2) asm volatile("s_waitcnt vmcnt(4)" ::: "memory");  // t+1 landed; t+2 in flight
      else     asm volatile("s_waitcnt vmcnt(0)" ::: "memory");  // tail drain
      BAR();
    }
  }
#undef SA
#undef SB
}

// ---------- paired dispatch: gemm2(e2, one token-half) + gemm1(e1, other half) ----------
__global__ __launch_bounds__(512, 2) void k_pair(const u16* __restrict__ xb,
                                                 const u16* __restrict__ w1b,
                                                 const float* __restrict__ b1,
                                                 const u16* __restrict__ w2b,
                                                 const float* __restrict__ b2,
                                                 const float* __restrict__ probs,
                                                 float* __restrict__ out,
                                                 const u16* __restrict__ hbR,
                                                 u16* __restrict__ hbW,
                                                 int e2, int t02,
                                                 int e1, int t01, int mt1, int n2){
  __shared__ alignas(16) u16 lds[65536];   // 128 KiB: 2 bufs x (A 16384 | B 16384 elems)
  const int tid = threadIdx.x;
  const int l  = tid & 63, w = tid >> 6;
  const int wr = w >> 2,  wc = w & 3;
  const int g4 = l >> 4,  ln = l & 15;
  const int bx = (int)blockIdx.x;
  f32x4 acc[8][4] = {};

  if (bx < n2){
    // ---- gemm2: XCD-chunked, y-fastest (3 N-tiles share the A-panel) ----
    const int wg = xcd_chunk(bx, n2);
    const int tx = wg / 3, ty = wg % 3;
    const int m0 = tx << 8, n0 = ty << 8;
    gemm256(hbR + (long)m0 * H_DIM, H_DIM,
            w2b + ((long)e2 * D_DIM + n0) * H_DIM, H_DIM,
            48, lds, tid, acc);
    float bias[4];
#pragma unroll
    for (int ni = 0; ni < 4; ++ni) bias[ni] = b2[(long)e2*D_DIM + n0 + wc*64 + ni*16 + ln];
#pragma unroll
    for (int mi = 0; mi < 8; ++mi){
#pragma unroll
      for (int j = 0; j < 4; ++j){
        const int gt = t02 + m0 + wr*128 + mi*16 + g4*4 + j;
        if (gt < (int)T_TOK){
          const float p = probs[(long)gt*8 + e2];
          float* dst = out + (long)gt * D_DIM + n0 + wc*64;
#pragma unroll
          for (int ni = 0; ni < 4; ++ni){
            const float v = p * (acc[mi][ni][j] + bias[ni]);
            if (e2 == 0) dst[ni*16 + ln] = v;
            else         dst[ni*16 + ln] += v;
          }
        }
      }
    }
  } else {
    // ---- gemm1: XCD-chunked, x-fastest (B-panel reused along chunk) ----
    const int n1 = (int)gridDim.x - n2;
    const int wg = xcd_chunk(bx - n2, n1);
    const int tx = wg % mt1, ty = wg / mt1;
    const int m0 = tx << 8, n0 = ty << 8;
    gemm256(xb + (long)(t01 + m0) * D_DIM, D_DIM,
            w1b + ((long)e1 * H_DIM + n0) * D_DIM, D_DIM,
            12, lds, tid, acc);
    float bias[4];
#pragma unroll
    for (int ni = 0; ni < 4; ++ni) bias[ni] = b1[(long)e1*H_DIM + n0 + wc*64 + ni*16 + ln];
#pragma unroll
    for (int mi = 0; mi < 8; ++mi){
#pragma unroll
      for (int j = 0; j < 4; ++j){
        const int r = m0 + wr*128 + mi*16 + g4*4 + j;     // half-local row
        u16* dst = hbW + (long)r * H_DIM + n0 + wc*64;
#pragma unroll
        for (int ni = 0; ni < 4; ++ni){
          const float v  = acc[mi][ni][j] + bias[ni];
          const float gl = v / (1.0f + __expf(-1.702f * v));  // quick_gelu
          dst[ni*16 + ln] = f2bf(gl);
        }
      }
    }
  }
}

// ---------- host ----------
extern "C" void kernel_launch(void* const* d_in, const int* in_sizes, int n_in,
                              void* d_out, int out_size, void* d_ws, size_t ws_size,
                              hipStream_t stream){
  const float* x  = (const float*)d_in[0];
  const float* W1 = (const float*)d_in[1];
  const float* b1 = (const float*)d_in[2];
  const float* W2 = (const float*)d_in[3];
  const float* b2 = (const float*)d_in[4];
  const float* Wr = (const float*)d_in[5];
  const float* br = (const float*)d_in[6];
  float* out = (float*)d_out;

  char* ws = (char*)d_ws;
  size_t off = 0;
  auto carve = [&](size_t bytes)->void*{
    void* p = ws + off; off += (bytes + 255) & ~(size_t)255; return p;
  };
  u16*   xb    = (u16*)  carve((size_t)M_PAD * D_DIM * 2);
  u16*   w1b   = (u16*)  carve((size_t)E_NUM * H_DIM * D_DIM * 2);
  u16*   w2b   = (u16*)  carve((size_t)E_NUM * D_DIM * H_DIM * 2);
  float* probs = (float*)carve((size_t)T_TOK * E_NUM * 4);
  u16*   hbA   = (u16*)  carve((size_t)8192 * H_DIM * 2);   // tokens [0, 8192)
  u16*   hbB   = (u16*)  carve((size_t)8448 * H_DIM * 2);   // tokens [8192, 16640)

  // conversions + router
  k_conv<<<dim3(2048), dim3(256), 0, stream>>>(x,  xb,  T_TOK*D_DIM, M_PAD*D_DIM);
  k_conv<<<dim3(2048), dim3(256), 0, stream>>>(W1, w1b, E_NUM*H_DIM*D_DIM, E_NUM*H_DIM*D_DIM);
  k_conv<<<dim3(2048), dim3(256), 0, stream>>>(W2, w2b, E_NUM*D_DIM*H_DIM, E_NUM*D_DIM*H_DIM);
  k_router<<<dim3(4112), dim3(256), 0, stream>>>(x, Wr, br, probs);

  const int MTA = 32, MTB = 33;      // 256-row tile counts per token-half
  const int T0A = 0,  T0B = 8192;

  auto pair = [&](int e2, const u16* hbR, int t02, int mt2,
                  int e1, u16* hbW, int t01, int mt1){
    const int n2 = mt2 * 3, n1 = mt1 * 12;
    k_pair<<<dim3((unsigned)(n2 + n1)), dim3(512), 0, stream>>>(
        xb, w1b, b1, w2b, b2, probs, out, hbR, hbW,
        e2, t02, e1, t01, mt1, n2);
  };

  // ping-pong: D0: g1(0,A); D(2e+1): g2(e,A)+g1(e,B); D(2e+2): g2(e,B)+g1(e+1,A); D16: g2(7,B)
  pair(0, nullptr, 0, 0, 0, hbA, T0A, MTA);
  for (int e = 0; e < 8; ++e){
    pair(e, hbA, T0A, MTA, e, hbB, T0B, MTB);
    if (e < 7) pair(e, hbB, T0B, MTB, e + 1, hbA, T0A, MTA);
  }
  pair(7, hbB, T0B, MTB, 0, nullptr, 0, 0);
}